// Round 12
// baseline (77.365 us; speedup 1.0000x reference)
//
#include <hip/hip_runtime.h>

// MelMeanFilteredMSE: out = mean( (M @ (10^(mo/10) - 10^(tg/10)))^2 )
// M is a banded variable-width mean filter (width <= 21, band monotone).
// Sliding-window running sum along frequency; one pass over 268 MB inputs.
// R12: keep R9's float4/NSEG=12/768-block structure (5.9 TB/s delivered).
//      Cut fixed overhead: (1) analytic stream bounds [i0-10, i1+10) ->
//      first loads hoisted above the band-extraction prologue (latency
//      overlap); (2) final reduction fused via last-block pattern
//      (device-scope atomics, deterministic fixed-order sum), one launch.

#define F 1025
#define TT 2048
#define BB 16
#define NSEG 12
#define SEG 86            // ceil(F / NSEG)
#define RING 24           // >= max live window span (<=22), proven from mel construction
#define TPB 128
#define TCH 512           // columns per block (float4 per thread)
#define NTB (TT / TCH)    // 4
#define NBLK (BB * NTB * NSEG)  // 768 = 3 blocks/CU exactly
#define CHUNK 4
#define HALF 10           // max filter half-width: fs<=21 -> band within [i-10, i+10]

__global__ __launch_bounds__(TPB, 2) void mel_mse_kernel(const float* __restrict__ mo,
                                                         const float* __restrict__ tg,
                                                         const float* __restrict__ mtx,
                                                         double* __restrict__ partial,
                                                         unsigned int* __restrict__ counter,
                                                         float* __restrict__ out) {
    const int tid = threadIdx.x;
    const int blk = blockIdx.x;
    const int s  = blk % NSEG;
    const int r_ = blk / NSEG;
    const int tb = r_ % NTB;
    const int b  = r_ / NTB;

    const int i0 = s * SEG;
    const int i1 = (i0 + SEG < F) ? (i0 + SEG) : F;
    const int nrows = i1 - i0;                 // 86 (79 for last seg)

    // Analytic stream bounds (independent of matrix contents):
    const int jA = (i0 - HALF > 0) ? (i0 - HALF) : 0;
    const int jE = (i1 + HALF < F) ? (i1 + HALF) : F;

    __shared__ float4 ring[RING * TPB];        // 48 KB
    __shared__ int    be_l[SEG];
    __shared__ int    bs_l[SEG];
    __shared__ float  binv_l[SEG];

    const int ct = tb * TPB + tid;             // float4 column index [0, TT/4)
    const float4* __restrict__ moP = (const float4*)(mo + (size_t)b * F * TT) + ct;
    const float4* __restrict__ tgP = (const float4*)(tg + (size_t)b * F * TT) + ct;
    const size_t rs = TT / 4;                  // row stride in float4

    // 3-buffer chunk pipeline — first loads issued BEFORE the band scan so
    // HBM latency overlaps the prologue.
    float4 A0[CHUNK], G0[CHUNK], A1[CHUNK], G1[CHUNK], A2[CHUNK], G2[CHUNK];

#define LOADC(Ad, Gd, jbase)                                        \
    _Pragma("unroll")                                               \
    for (int r = 0; r < CHUNK; ++r) {                               \
        int jr = (jbase) + r;                                       \
        jr = (jr < jE) ? jr : (jE - 1);                             \
        Ad[r] = moP[(size_t)jr * rs];                               \
        Gd[r] = tgP[(size_t)jr * rs];                               \
    }

    LOADC(A0, G0, jA)
    LOADC(A1, G1, jA + CHUNK)

    // Band extraction: row i's nonzeros lie within [i-HALF, i+HALF].
    if (tid < nrows) {
        const int i  = i0 + tid;
        const int c0 = (i - HALF > 0) ? (i - HALF) : 0;
        const int c1 = (i + HALF + 1 < F) ? (i + HALF + 1) : F;
        const float* mrow = mtx + (size_t)i * F;
        int first = -1, last = -1;
        float fv = 0.0f;
        for (int c = c0; c < c1; ++c) {
            const float v = mrow[c];
            if (v != 0.0f) {
                if (first < 0) { first = c; fv = v; }
                last = c;
            }
        }
        bs_l[tid]   = first;
        be_l[tid]   = last + 1;
        binv_l[tid] = fv;                      // matrix stores 1/(end-start)
    }
    __syncthreads();

    const float C = 0.33219281f;               // log2(10)/10

    float wx = 0.0f, wy = 0.0f, wz = 0.0f, ww = 0.0f, acc = 0.0f;
    int i = 0, cs = jA, wp = 0, rp = 0;

    for (int j = jA; j < jE; j += CHUNK) {
        LOADC(A2, G2, j + 2 * CHUNK)           // issue 2 chunks (8 rows) ahead
        #pragma unroll
        for (int r = 0; r < CHUNK; ++r) {
            if (j + r < jE) {                  // wave-uniform guard
                const float dx = __builtin_amdgcn_exp2f(A0[r].x * C)
                               - __builtin_amdgcn_exp2f(G0[r].x * C);
                const float dy = __builtin_amdgcn_exp2f(A0[r].y * C)
                               - __builtin_amdgcn_exp2f(G0[r].y * C);
                const float dz = __builtin_amdgcn_exp2f(A0[r].z * C)
                               - __builtin_amdgcn_exp2f(G0[r].z * C);
                const float dw = __builtin_amdgcn_exp2f(A0[r].w * C)
                               - __builtin_amdgcn_exp2f(G0[r].w * C);
                float4 dv; dv.x = dx; dv.y = dy; dv.z = dz; dv.w = dw;
                ring[wp + tid] = dv;
                wp += TPB; if (wp == RING * TPB) wp = 0;
                wx += dx; wy += dy; wz += dz; ww += dw;
                while (i < nrows && be_l[i] <= j + r + 1) {
                    const int si = bs_l[i];
                    while (cs < si) {          // shrink window from below
                        const float4 o = ring[rp + tid];
                        rp += TPB; if (rp == RING * TPB) rp = 0;
                        wx -= o.x; wy -= o.y; wz -= o.z; ww -= o.w;
                        ++cs;
                    }
                    const float inv = binv_l[i];
                    const float fx = wx * inv, fy = wy * inv;
                    const float fz = wz * inv, fw = ww * inv;
                    acc = fmaf(fx, fx, fmaf(fy, fy, fmaf(fz, fz, fmaf(fw, fw, acc))));
                    ++i;
                }
            }
        }
        #pragma unroll
        for (int r = 0; r < CHUNK; ++r) {      // rotate buffers (static idx)
            A0[r] = A1[r]; G0[r] = G1[r];
            A1[r] = A2[r]; G1[r] = G2[r];
        }
    }
#undef LOADC

    // block reduction (float within wave, double across waves)
    #pragma unroll
    for (int off = 32; off > 0; off >>= 1)
        acc += __shfl_down(acc, off, 64);

    __shared__ double wred[2];
    __shared__ int s_done;
    const int wid = tid >> 6, lane = tid & 63;
    if (lane == 0) wred[wid] = (double)acc;
    __syncthreads();
    if (tid == 0) {
        const double ps = wred[0] + wred[1];
        atomicExch((unsigned long long*)&partial[blk], __double_as_longlong(ps));
        __threadfence();                       // data visible before counter bump
        const unsigned int prev = atomicAdd(counter, 1u);
        s_done = (prev == (unsigned int)(NBLK - 1));
    }
    __syncthreads();

    // Last-arriving block performs the final reduction (deterministic:
    // fixed strided order + fixed tree, regardless of which block runs it).
    if (s_done) {
        double sum = 0.0;
        for (int k = tid; k < NBLK; k += TPB) {
            const unsigned long long bits =
                atomicAdd((unsigned long long*)&partial[k], 0ULL);  // coherent load
            sum += __longlong_as_double(bits);
        }
        #pragma unroll
        for (int off = 32; off > 0; off >>= 1)
            sum += __shfl_down(sum, off, 64);
        __shared__ double w2[2];
        if (lane == 0) w2[wid] = sum;
        __syncthreads();
        if (tid == 0) {
            const double tot = w2[0] + w2[1];
            out[0] = (float)(tot / ((double)BB * (double)F * (double)TT));
        }
    }
}

extern "C" void kernel_launch(void* const* d_in, const int* in_sizes, int n_in,
                              void* d_out, int out_size, void* d_ws, size_t ws_size,
                              hipStream_t stream) {
    const float* mo  = (const float*)d_in[0];
    const float* tg  = (const float*)d_in[1];
    const float* mtx = (const float*)d_in[2];

    char* ws = (char*)d_ws;
    double*       partial = (double*)ws;               // 768 doubles
    unsigned int* counter = (unsigned int*)(ws + 8192);

    hipMemsetAsync(counter, 0, sizeof(unsigned int), stream);
    mel_mse_kernel<<<NBLK, TPB, 0, stream>>>(mo, tg, mtx, partial, counter,
                                             (float*)d_out);
}

// Round 13
// 63.392 us; speedup vs baseline: 1.2204x; 1.2204x over previous
//
#include <hip/hip_runtime.h>

// MelMeanFilteredMSE: out = mean( (M @ (10^(mo/10) - 10^(tg/10)))^2 )
// M is a banded variable-width mean filter (width <= 21, band monotone).
// Sliding-window running sum along frequency; one pass over 268 MB inputs.
// R13 = exact revert to R11 (best, 63.6 us): float4 16 B/lane, NSEG=12,
//     768 blocks = 3/CU, inline band scan with tight data-derived bounds,
//     separate tiny final-reduction kernel. R12's analytic-bounds hoist
//     (+9 MB fetch) and atomic last-block fusion (threadfence cost) both
//     regressed and are reverted.

#define F 1025
#define TT 2048
#define BB 16
#define NSEG 12
#define SEG 86            // ceil(F / NSEG)
#define RING 24           // >= max live window span (<=22), proven from mel construction
#define TPB 128
#define TCH 512           // columns per block (float4 per thread)
#define NTB (TT / TCH)    // 4
#define NBLK (BB * NTB * NSEG)  // 768 = 3 blocks/CU exactly
#define CHUNK 4
#define HALF 10           // max filter half-width: fs<=21 -> band within [i-10, i+10]

// ---- kernel 1: main pass (band schedule extracted inline per block).
__global__ __launch_bounds__(TPB, 2) void mel_mse_kernel(const float* __restrict__ mo,
                                                         const float* __restrict__ tg,
                                                         const float* __restrict__ mtx,
                                                         double* __restrict__ partial) {
    const int tid = threadIdx.x;
    const int blk = blockIdx.x;
    const int s  = blk % NSEG;
    const int r_ = blk / NSEG;
    const int tb = r_ % NTB;
    const int b  = r_ / NTB;

    const int i0 = s * SEG;
    const int i1 = (i0 + SEG < F) ? (i0 + SEG) : F;
    const int nrows = i1 - i0;                 // 86 (79 for last seg)

    __shared__ float4 ring[RING * TPB];        // 48 KB
    __shared__ int    be_l[SEG];
    __shared__ int    bs_l[SEG];
    __shared__ float  binv_l[SEG];

    // Inline band extraction: row i's nonzeros lie within [i-HALF, i+HALF]
    // (fs <= 21). Scan the diagonal band of the matrix; exact by construction.
    for (int k = tid; k < nrows; k += TPB) {
        const int i  = i0 + k;
        const int c0 = (i - HALF > 0) ? (i - HALF) : 0;
        const int c1 = (i + HALF + 1 < F) ? (i + HALF + 1) : F;
        const float* mrow = mtx + (size_t)i * F;
        int first = -1, last = -1;
        float fv = 0.0f;
        for (int c = c0; c < c1; ++c) {
            const float v = mrow[c];
            if (v != 0.0f) {
                if (first < 0) { first = c; fv = v; }
                last = c;
            }
        }
        bs_l[k]   = first;
        be_l[k]   = last + 1;
        binv_l[k] = fv;                        // matrix stores 1/(end-start)
    }
    __syncthreads();

    const int jstart = bs_l[0];
    const int jend   = be_l[nrows - 1];

    const int ct = tb * TPB + tid;             // float4 column index [0, TT/4)
    const float4* __restrict__ moP = (const float4*)(mo + (size_t)b * F * TT) + ct;
    const float4* __restrict__ tgP = (const float4*)(tg + (size_t)b * F * TT) + ct;
    const size_t rs = TT / 4;                  // row stride in float4

    const float C = 0.33219281f;               // log2(10)/10

    // 3-buffer chunk pipeline (loads issued 2 chunks = 8 rows ahead)
    float4 A0[CHUNK], G0[CHUNK], A1[CHUNK], G1[CHUNK], A2[CHUNK], G2[CHUNK];

#define LOADC(Ad, Gd, jbase)                                        \
    _Pragma("unroll")                                               \
    for (int r = 0; r < CHUNK; ++r) {                               \
        int jr = (jbase) + r;                                       \
        jr = (jr < jend) ? jr : (jend - 1);                         \
        Ad[r] = moP[(size_t)jr * rs];                               \
        Gd[r] = tgP[(size_t)jr * rs];                               \
    }

    LOADC(A0, G0, jstart)
    LOADC(A1, G1, jstart + CHUNK)

    float wx = 0.0f, wy = 0.0f, wz = 0.0f, ww = 0.0f, acc = 0.0f;
    int i = 0, cs = jstart, wp = 0, rp = 0;

    for (int j = jstart; j < jend; j += CHUNK) {
        LOADC(A2, G2, j + 2 * CHUNK)           // issue 2 chunks (8 rows) ahead
        #pragma unroll
        for (int r = 0; r < CHUNK; ++r) {
            if (j + r < jend) {                // wave-uniform guard
                const float dx = __builtin_amdgcn_exp2f(A0[r].x * C)
                               - __builtin_amdgcn_exp2f(G0[r].x * C);
                const float dy = __builtin_amdgcn_exp2f(A0[r].y * C)
                               - __builtin_amdgcn_exp2f(G0[r].y * C);
                const float dz = __builtin_amdgcn_exp2f(A0[r].z * C)
                               - __builtin_amdgcn_exp2f(G0[r].z * C);
                const float dw = __builtin_amdgcn_exp2f(A0[r].w * C)
                               - __builtin_amdgcn_exp2f(G0[r].w * C);
                float4 dv; dv.x = dx; dv.y = dy; dv.z = dz; dv.w = dw;
                ring[wp + tid] = dv;
                wp += TPB; if (wp == RING * TPB) wp = 0;
                wx += dx; wy += dy; wz += dz; ww += dw;
                while (i < nrows && be_l[i] <= j + r + 1) {
                    const int si = bs_l[i];
                    while (cs < si) {          // shrink window from below
                        const float4 o = ring[rp + tid];
                        rp += TPB; if (rp == RING * TPB) rp = 0;
                        wx -= o.x; wy -= o.y; wz -= o.z; ww -= o.w;
                        ++cs;
                    }
                    const float inv = binv_l[i];
                    const float fx = wx * inv, fy = wy * inv;
                    const float fz = wz * inv, fw = ww * inv;
                    acc = fmaf(fx, fx, fmaf(fy, fy, fmaf(fz, fz, fmaf(fw, fw, acc))));
                    ++i;
                }
            }
        }
        #pragma unroll
        for (int r = 0; r < CHUNK; ++r) {      // rotate buffers (static idx)
            A0[r] = A1[r]; G0[r] = G1[r];
            A1[r] = A2[r]; G1[r] = G2[r];
        }
    }
#undef LOADC

    // block reduction (float within wave, double across waves)
    #pragma unroll
    for (int off = 32; off > 0; off >>= 1)
        acc += __shfl_down(acc, off, 64);

    __shared__ double wred[2];
    const int wid = tid >> 6, lane = tid & 63;
    if (lane == 0) wred[wid] = (double)acc;
    __syncthreads();
    if (tid == 0)
        partial[blk] = wred[0] + wred[1];
}

// ---- kernel 2: final reduction -> scalar mean
__global__ __launch_bounds__(256) void final_kernel(const double* __restrict__ partial,
                                                    float* __restrict__ out) {
    const int tid = threadIdx.x;
    double s = 0.0;
    for (int k = tid; k < NBLK; k += 256) s += partial[k];
    #pragma unroll
    for (int off = 32; off > 0; off >>= 1)
        s += __shfl_down(s, off, 64);
    __shared__ double wred[4];
    const int wid = tid >> 6, lane = tid & 63;
    if (lane == 0) wred[wid] = s;
    __syncthreads();
    if (tid == 0) {
        double tot = wred[0] + wred[1] + wred[2] + wred[3];
        out[0] = (float)(tot / ((double)BB * (double)F * (double)TT));
    }
}

extern "C" void kernel_launch(void* const* d_in, const int* in_sizes, int n_in,
                              void* d_out, int out_size, void* d_ws, size_t ws_size,
                              hipStream_t stream) {
    const float* mo  = (const float*)d_in[0];
    const float* tg  = (const float*)d_in[1];
    const float* mtx = (const float*)d_in[2];

    double* partial = (double*)d_ws;           // 768 doubles

    mel_mse_kernel<<<NBLK, TPB, 0, stream>>>(mo, tg, mtx, partial);
    final_kernel<<<1, 256, 0, stream>>>(partial, (float*)d_out);
}